// Round 9
// baseline (58.765 us; speedup 1.0000x reference)
//
#include <hip/hip_runtime.h>
#include <hip/hip_fp16.h>

#define NPTS 262144
#define EMB  256
#define NROWS 2048

typedef _Float16 half_t;
typedef __attribute__((ext_vector_type(2))) _Float16 half2v;

// ---------------------------------------------------------------------------
// Kernel 1: T8[a,i,o] = fp8_e4m3( 64 * (30/4)/(2pi) * sum_e tables[a,i,e]*W1[o,e] )
// Row = 256 fp8 = 256 B. Packed via LDS repack stage.
// ---------------------------------------------------------------------------
__global__ __launch_bounds__(256) void t8_precompute_kernel(
    const float* __restrict__ tables,   // [4][512][256]
    const float* __restrict__ W1,       // [256][256]
    unsigned int* __restrict__ T8)      // [2048][64] dwords (fp8 bytes)
{
    __shared__ __align__(16) float arow[8][EMB];
    __shared__ __align__(16) float prow[8][EMB];
    const int row0 = blockIdx.x * 8;
    const int o = threadIdx.x;

    #pragma unroll
    for (int r = 0; r < 8; ++r)
        arow[r][o] = tables[(row0 + r) * EMB + o];
    __syncthreads();

    float acc[8] = {0.f, 0.f, 0.f, 0.f, 0.f, 0.f, 0.f, 0.f};
    const float4* __restrict__ w1v = reinterpret_cast<const float4*>(W1 + o * EMB);
    for (int ec = 0; ec < EMB / 4; ++ec) {
        const float4 w4 = w1v[ec];
        #pragma unroll
        for (int r = 0; r < 8; ++r) {
            const float4 a4 = *reinterpret_cast<const float4*>(&arow[r][ec * 4]);
            acc[r] = fmaf(w4.x, a4.x, acc[r]);
            acc[r] = fmaf(w4.y, a4.y, acc[r]);
            acc[r] = fmaf(w4.z, a4.z, acc[r]);
            acc[r] = fmaf(w4.w, a4.w, acc[r]);
        }
    }
    const float s = 64.f * 7.5f * 0.15915494309189535f;   // 64*(30/4)/(2pi)
    #pragma unroll
    for (int r = 0; r < 8; ++r)
        prow[r][o] = s * acc[r];
    __syncthreads();

    // repack: 8 rows x 64 dwords = 512 dwords; 2 per thread
    #pragma unroll
    for (int hh = 0; hh < 2; ++hh) {
        const int gidx = o + hh * 256;        // 0..511
        const int r    = gidx >> 6;
        const int dw   = gidx & 63;
        const float* p = &prow[r][dw * 4];
        int v = __builtin_amdgcn_cvt_pk_fp8_f32(p[0], p[1], 0, false);
        v     = __builtin_amdgcn_cvt_pk_fp8_f32(p[2], p[3], v, true);
        T8[(row0 + r) * 64 + dw] = (unsigned int)v;
    }
}

// ---------------------------------------------------------------------------
// DPP butterfly add over 16 lanes — VALU pipe.
// ---------------------------------------------------------------------------
template <int CTRL>
__device__ __forceinline__ float dpp_add(float v) {
    const int vi = __builtin_bit_cast(int, v);
    const int sh = __builtin_amdgcn_update_dpp(0, vi, CTRL, 0xF, 0xF, true);
    return v + __builtin_bit_cast(float, sh);
}
__device__ __forceinline__ float reduce16(float v) {
    v = dpp_add<0xB1>(v);
    v = dpp_add<0x4E>(v);
    v = dpp_add<0x141>(v);
    v = dpp_add<0x140>(v);
    return v;
}

// ---------------------------------------------------------------------------
// Kernel 2: 16 lanes/point, lane owns 16 dims (16 B fp8 = full-row dense),
// 4 points/wave, 8 fully-unrolled iterations, 2-deep double-buffered pipeline.
// ---------------------------------------------------------------------------
__global__ __launch_bounds__(256, 3) void eval_kernel(
    const float* __restrict__ coords,      // [N][2]
    const char* __restrict__ T8b,          // [2048][256] fp8 bytes
    const float* __restrict__ b1,
    const float* __restrict__ W2,
    const float* __restrict__ b2,
    float* __restrict__ out)
{
    const int lane = threadIdx.x & 63;
    const int g    = lane >> 4;            // point slot within wave
    const int l16  = lane & 15;
    const int d0   = l16 * 16;             // 16 embedding dims per lane

    const int wave   = blockIdx.x * 4 + (threadIdx.x >> 6);
    const int stride = gridDim.x * 4;      // 8192

    // ---- hoisted constants ----
    const float sb  = 30.f * 0.15915494309189535f;
    const float c64 = 0.015625f;           // 1/64 (fp8 scale undo)
    half_t biash[16];
    #pragma unroll
    for (int i = 0; i < 16; ++i) biash[i] = (half_t)(sb * b1[d0 + i]);
    half2v w2p[3][8];
    #pragma unroll
    for (int j = 0; j < 3; ++j)
        #pragma unroll
        for (int k = 0; k < 8; ++k) {
            w2p[j][k][0] = (half_t)W2[j * EMB + d0 + 2 * k];
            w2p[j][k][1] = (half_t)W2[j * EMB + d0 + 2 * k + 1];
        }
    const float ob0 = b2[0], ob1 = b2[1], ob2 = b2[2];
    const int laneoff = l16 << 4;
    const float TMAX = 0.9995f * 511.0f;

    // ---- pipeline state (double-buffered, static indices only) ----
    int    rb[2][4];
    half2v wg[2][4];      // (1-w, w) packed fp16 -> fma_mix operands
    int    pC[2];
    uint4  R0[2][4], R1[2][4];

    auto calc = [&](int pq, int s) {
        const int p = 4 * pq + g;
        pC[s] = p;
        const float2 cf = *reinterpret_cast<const float2*>(coords + 2 * p);
        const float txr = __builtin_amdgcn_fmed3f(fmaf(cf.x, 255.5f, 255.5f), 0.f, 511.f);
        const float tyr = __builtin_amdgcn_fmed3f(fmaf(cf.y, 255.5f, 255.5f), 0.f, 511.f);
        float t[4];
        t[0] = fminf(txr, TMAX);
        t[1] = fminf(tyr, TMAX);
        t[2] = fminf((txr + tyr) * 0.5f, TMAX);
        t[3] = fminf(fmaf(txr - tyr, 0.5f, 255.5f), TMAX);
        #pragma unroll
        for (int a = 0; a < 4; ++a) {
            const int i0  = (int)t[a];
            const float w = t[a] - (float)i0;
            rb[s][a] = (((a << 9) + i0) << 8) + laneoff;
            wg[s][a] = __builtin_bit_cast(half2v,
                           __builtin_amdgcn_cvt_pkrtz(1.f - w, w));
        }
    };
    auto loads = [&](int s) {
        #pragma unroll
        for (int a = 0; a < 4; ++a) {
            R0[s][a] = *reinterpret_cast<const uint4*>(T8b + rb[s][a]);
            R1[s][a] = *reinterpret_cast<const uint4*>(T8b + rb[s][a] + 256);
        }
    };

    calc(wave, 0);
    loads(0);

    #pragma unroll
    for (int k = 0; k < 8; ++k) {
        const int s  = k & 1;
        const int ns = s ^ 1;
        if (k < 7) { calc(wave + (k + 1) * stride, ns); loads(ns); }

        // ---- unpack fp8 -> f32 and lerp (exact f32 accumulation) ----
        float acc[16];
        #pragma unroll
        for (int i = 0; i < 16; ++i) acc[i] = 0.f;
        #pragma unroll
        for (int a = 0; a < 4; ++a) {
            const float omw = (float)wg[s][a][0];
            const float w   = (float)wg[s][a][1];
            const unsigned int* u0 = reinterpret_cast<const unsigned int*>(&R0[s][a]);
            const unsigned int* u1 = reinterpret_cast<const unsigned int*>(&R1[s][a]);
            #pragma unroll
            for (int q = 0; q < 4; ++q) {
                auto p0l = __builtin_amdgcn_cvt_pk_f32_fp8(u0[q], false);
                auto p0h = __builtin_amdgcn_cvt_pk_f32_fp8(u0[q], true);
                auto p1l = __builtin_amdgcn_cvt_pk_f32_fp8(u1[q], false);
                auto p1h = __builtin_amdgcn_cvt_pk_f32_fp8(u1[q], true);
                acc[4*q+0] = fmaf(p0l[0], omw, acc[4*q+0]);
                acc[4*q+0] = fmaf(p1l[0], w,   acc[4*q+0]);
                acc[4*q+1] = fmaf(p0l[1], omw, acc[4*q+1]);
                acc[4*q+1] = fmaf(p1l[1], w,   acc[4*q+1]);
                acc[4*q+2] = fmaf(p0h[0], omw, acc[4*q+2]);
                acc[4*q+2] = fmaf(p1h[0], w,   acc[4*q+2]);
                acc[4*q+3] = fmaf(p0h[1], omw, acc[4*q+3]);
                acc[4*q+3] = fmaf(p1h[1], w,   acc[4*q+3]);
            }
        }

        // ---- sin + output dots ----
        float q0 = 0.f, q1 = 0.f, q2 = 0.f;
        #pragma unroll
        for (int kk = 0; kk < 8; ++kk) {
            const float a0 = fmaf(acc[2*kk],   c64, (float)biash[2*kk]);
            const float a1 = fmaf(acc[2*kk+1], c64, (float)biash[2*kk+1]);
            const float s0 = __builtin_amdgcn_sinf(a0);
            const float s1 = __builtin_amdgcn_sinf(a1);
            const half2v hp = __builtin_bit_cast(half2v,
                                  __builtin_amdgcn_cvt_pkrtz(s0, s1));
            q0 = __builtin_amdgcn_fdot2(hp, w2p[0][kk], q0, false);
            q1 = __builtin_amdgcn_fdot2(hp, w2p[1][kk], q1, false);
            q2 = __builtin_amdgcn_fdot2(hp, w2p[2][kk], q2, false);
        }

        q0 = reduce16(q0);
        q1 = reduce16(q1);
        q2 = reduce16(q2);

        if (l16 == 0) {
            *reinterpret_cast<float3*>(out + 3 * pC[s]) =
                make_float3(q0 + ob0, q1 + ob1, q2 + ob2);
        }
    }
}

extern "C" void kernel_launch(void* const* d_in, const int* in_sizes, int n_in,
                              void* d_out, int out_size, void* d_ws, size_t ws_size,
                              hipStream_t stream) {
    const float* coords = (const float*)d_in[0];
    const float* tables = (const float*)d_in[1];
    const float* W1     = (const float*)d_in[2];
    const float* b1     = (const float*)d_in[3];
    const float* W2     = (const float*)d_in[4];
    const float* b2     = (const float*)d_in[5];
    float* out = (float*)d_out;

    unsigned int* T8 = (unsigned int*)d_ws;   // 2048*256 B = 512 KiB scratch

    hipLaunchKernelGGL(t8_precompute_kernel, dim3(NROWS / 8), dim3(256), 0, stream,
                       tables, W1, T8);
    hipLaunchKernelGGL(eval_kernel, dim3(2048), dim3(256), 0, stream,
                       coords, (const char*)T8, b1, W2, b2, out);
}

// Round 10
// 58.370 us; speedup vs baseline: 1.0068x; 1.0068x over previous
//
#include <hip/hip_runtime.h>
#include <hip/hip_fp16.h>

#define NPTS 262144
#define EMB  256
#define NROWS 2048

typedef _Float16 half_t;
typedef __attribute__((ext_vector_type(8))) _Float16 half8;
typedef __attribute__((ext_vector_type(2))) _Float16 half2v;

// ---------------------------------------------------------------------------
// Kernel 1: T2[a,i,o] = (30/4)/(2pi) * sum_e tables[a,i,e] * W1[o,e], fp16.
// ---------------------------------------------------------------------------
__global__ __launch_bounds__(256) void t2_precompute_kernel(
    const float* __restrict__ tables,   // [4][512][256]
    const float* __restrict__ W1,       // [256][256]
    half_t* __restrict__ T2)            // [2048][256]
{
    __shared__ __align__(16) float arow[8][EMB];
    const int row0 = blockIdx.x * 8;
    const int o = threadIdx.x;

    #pragma unroll
    for (int r = 0; r < 8; ++r)
        arow[r][o] = tables[(row0 + r) * EMB + o];
    __syncthreads();

    float acc[8] = {0.f, 0.f, 0.f, 0.f, 0.f, 0.f, 0.f, 0.f};
    const float4* __restrict__ w1v = reinterpret_cast<const float4*>(W1 + o * EMB);
    for (int ec = 0; ec < EMB / 4; ++ec) {
        const float4 w4 = w1v[ec];
        #pragma unroll
        for (int r = 0; r < 8; ++r) {
            const float4 a4 = *reinterpret_cast<const float4*>(&arow[r][ec * 4]);
            acc[r] = fmaf(w4.x, a4.x, acc[r]);
            acc[r] = fmaf(w4.y, a4.y, acc[r]);
            acc[r] = fmaf(w4.z, a4.z, acc[r]);
            acc[r] = fmaf(w4.w, a4.w, acc[r]);
        }
    }
    const float s = 7.5f * 0.15915494309189535f;   // (30/4)/(2pi)
    #pragma unroll
    for (int r = 0; r < 8; ++r)
        T2[(row0 + r) * EMB + o] = (half_t)(s * acc[r]);
}

// ---------------------------------------------------------------------------
// DPP butterfly add over 16 lanes — VALU pipe, no LDS traffic.
// ---------------------------------------------------------------------------
template <int CTRL>
__device__ __forceinline__ float dpp_add(float v) {
    const int vi = __builtin_bit_cast(int, v);
    const int sh = __builtin_amdgcn_update_dpp(0, vi, CTRL, 0xF, 0xF, true);
    return v + __builtin_bit_cast(float, sh);
}
__device__ __forceinline__ float reduce16(float v) {
    v = dpp_add<0xB1>(v);    // quad_perm xor1
    v = dpp_add<0x4E>(v);    // quad_perm xor2
    v = dpp_add<0x141>(v);   // row_half_mirror
    v = dpp_add<0x140>(v);   // row_mirror
    return v;
}

// ---------------------------------------------------------------------------
// Kernel 2: 16 lanes/point, 4 points/wave, 4 iterations/wave (grid 4096),
// fully unrolled 2-deep software pipeline. Plain __launch_bounds__(256) so
// the register allocator can keep the whole double-buffer live.
// ---------------------------------------------------------------------------
__global__ __launch_bounds__(256) void eval_kernel(
    const float* __restrict__ coords,      // [N][2]
    const half_t* __restrict__ T2,         // [2048][256]
    const float* __restrict__ b1,
    const float* __restrict__ W2,
    const float* __restrict__ b2,
    float* __restrict__ out)
{
    const int lane = threadIdx.x & 63;
    const int g    = lane >> 4;            // point slot within wave
    const int l16  = lane & 15;
    const int dA   = l16 * 8;              // dims dA..dA+7   (row half A)
    const int dB   = 128 + l16 * 8;        // dims dB..dB+7   (row half B)

    const int wave   = blockIdx.x * 4 + (threadIdx.x >> 6);
    const int stride = gridDim.x * 4;      // 16384

    // ---- hoisted constants ----
    const float sb = 30.f * 0.15915494309189535f;
    half8 biasA, biasB;
    #pragma unroll
    for (int i = 0; i < 8; ++i) {
        biasA[i] = (half_t)(sb * b1[dA + i]);
        biasB[i] = (half_t)(sb * b1[dB + i]);
    }
    half2v w2A[3][4], w2B[3][4];
    #pragma unroll
    for (int j = 0; j < 3; ++j)
        #pragma unroll
        for (int k = 0; k < 4; ++k) {
            w2A[j][k][0] = (half_t)W2[j * EMB + dA + 2 * k];
            w2A[j][k][1] = (half_t)W2[j * EMB + dA + 2 * k + 1];
            w2B[j][k][0] = (half_t)W2[j * EMB + dB + 2 * k];
            w2B[j][k][1] = (half_t)W2[j * EMB + dB + 2 * k + 1];
        }
    const float ob0 = b2[0], ob1 = b2[1], ob2 = b2[2];

    int Ca[4];
    #pragma unroll
    for (int a = 0; a < 4; ++a) Ca[a] = (a << 18) + (l16 << 4);

    const char* __restrict__ T2b = reinterpret_cast<const char*>(T2);
    const float TMAX = 0.9995f * 511.0f;

    // ---- per-iteration helpers ----
    auto calc = [&](int pq, int rb[4], half2v pw[4], int& pOut) {
        const int p = 4 * pq + g;
        pOut = p;
        const float2 cf = *reinterpret_cast<const float2*>(coords + 2 * p);
        const float txr = __builtin_amdgcn_fmed3f(fmaf(cf.x, 255.5f, 255.5f), 0.f, 511.f);
        const float tyr = __builtin_amdgcn_fmed3f(fmaf(cf.y, 255.5f, 255.5f), 0.f, 511.f);
        float t[4];
        t[0] = fminf(txr, TMAX);
        t[1] = fminf(tyr, TMAX);
        t[2] = fminf((txr + tyr) * 0.5f, TMAX);
        t[3] = fminf(fmaf(txr - tyr, 0.5f, 255.5f), TMAX);
        #pragma unroll
        for (int a = 0; a < 4; ++a) {
            const int i0 = (int)t[a];
            const float w = t[a] - (float)i0;
            rb[a] = (i0 << 9) + Ca[a];
            pw[a] = __builtin_bit_cast(half2v,
                        __builtin_amdgcn_cvt_pkrtz(1.f - w, w));
        }
    };
    auto loadA = [&](const int rb[4], half8 A0[4], half8 A1[4]) {
        #pragma unroll
        for (int a = 0; a < 4; ++a) {
            A0[a] = *reinterpret_cast<const half8*>(T2b + rb[a]);
            A1[a] = *reinterpret_cast<const half8*>(T2b + rb[a] + 512);
        }
    };
    auto loadB = [&](const int rb[4], half8 B0[4], half8 B1[4]) {
        #pragma unroll
        for (int a = 0; a < 4; ++a) {
            B0[a] = *reinterpret_cast<const half8*>(T2b + rb[a] + 256);
            B1[a] = *reinterpret_cast<const half8*>(T2b + rb[a] + 768);
        }
    };
    auto dots = [&](const half8& acc, const half2v (&w2)[3][4],
                    float& q0, float& q1, float& q2) {
        #pragma unroll
        for (int k = 0; k < 4; ++k) {
            const float s0 = __builtin_amdgcn_sinf((float)acc[2 * k]);
            const float s1 = __builtin_amdgcn_sinf((float)acc[2 * k + 1]);
            const half2v hp = __builtin_bit_cast(half2v,
                                  __builtin_amdgcn_cvt_pkrtz(s0, s1));
            q0 = __builtin_amdgcn_fdot2(hp, w2[0][k], q0, false);
            q1 = __builtin_amdgcn_fdot2(hp, w2[1][k], q1, false);
            q2 = __builtin_amdgcn_fdot2(hp, w2[2][k], q2, false);
        }
    };

    // ---- pipelined main loop (4 iterations, fully unrolled) ----
    int    rbC[4]; half2v pwC[4]; int pC;
    int    rbN[4]; half2v pwN[4]; int pN = 0;
    half8  A0[4], A1[4], B0[4], B1[4];

    calc(wave, rbC, pwC, pC);
    loadA(rbC, A0, A1);
    loadB(rbC, B0, B1);

    #pragma unroll
    for (int k = 0; k < 4; ++k) {
        if (k < 3) calc(wave + (k + 1) * stride, rbN, pwN, pN);

        half8 accA = biasA;
        #pragma unroll
        for (int a = 0; a < 4; ++a) {
            accA = A0[a] * pwC[a][0] + accA;
            accA = A1[a] * pwC[a][1] + accA;
        }
        if (k < 3) loadA(rbN, A0, A1);       // prefetch next A-half

        float q0 = 0.f, q1 = 0.f, q2 = 0.f;
        dots(accA, w2A, q0, q1, q2);

        half8 accB = biasB;
        #pragma unroll
        for (int a = 0; a < 4; ++a) {
            accB = B0[a] * pwC[a][0] + accB;
            accB = B1[a] * pwC[a][1] + accB;
        }
        if (k < 3) loadB(rbN, B0, B1);       // prefetch next B-half

        dots(accB, w2B, q0, q1, q2);

        q0 = reduce16(q0);
        q1 = reduce16(q1);
        q2 = reduce16(q2);

        if (l16 == 0) {
            *reinterpret_cast<float3*>(out + 3 * pC) =
                make_float3(q0 + ob0, q1 + ob1, q2 + ob2);
        }

        #pragma unroll
        for (int a = 0; a < 4; ++a) { rbC[a] = rbN[a]; pwC[a] = pwN[a]; }
        pC = pN;
    }
}

extern "C" void kernel_launch(void* const* d_in, const int* in_sizes, int n_in,
                              void* d_out, int out_size, void* d_ws, size_t ws_size,
                              hipStream_t stream) {
    const float* coords = (const float*)d_in[0];
    const float* tables = (const float*)d_in[1];
    const float* W1     = (const float*)d_in[2];
    const float* b1     = (const float*)d_in[3];
    const float* W2     = (const float*)d_in[4];
    const float* b2     = (const float*)d_in[5];
    float* out = (float*)d_out;

    half_t* T2 = (half_t*)d_ws;   // 1 MiB scratch

    hipLaunchKernelGGL(t2_precompute_kernel, dim3(NROWS / 8), dim3(256), 0, stream,
                       tables, W1, T2);
    hipLaunchKernelGGL(eval_kernel, dim3(4096), dim3(256), 0, stream,
                       coords, T2, b1, W2, b2, out);
}